// Round 15
// baseline (448.811 us; speedup 1.0000x reference)
//
#include <hip/hip_runtime.h>
#include <hip/hip_bf16.h>

// MapAgent: NatureCNN (3 convs + FC) -> map-write scan -> policy/value heads.
// T=32, B=64, TB=2048.
//
// R22 change (theory: conv123 is 65% stall (Mfma 13.7 + VALU 21%), HBM 12%.
// Last untried mechanism: per-wave MLP depth. Current schedule has 1 band
// (20KB/block) in flight; if HBM queueing latency > one compute phase, waves
// stall on vmcnt at every band write -> matches the idle signature):
//  * conv1 staging -> 3-band-deep register prefetch: prologue issues bands
//    0,1,2 (60KB/block outstanding); after band b's barrier, issue band b+3
//    while writing band b+1. Named sets fr0/1/2, fully unrolled (rule #20).
//    Each set dead (ds_writes issued) before reuse; barriers unchanged ->
//    bit-identical math. VGPR ~84 -> ~124 (under the 128 cliff).
//  * Everything else unchanged from R21.

#define TT 32
#define BB 64
#define TBR 2048

typedef _Float16 half_t;
typedef __attribute__((ext_vector_type(4))) _Float16 half4;
typedef __attribute__((ext_vector_type(8))) _Float16 half8;
typedef __attribute__((ext_vector_type(4))) float f32x4;

// ---- workspace offsets (floats) ----
#define OFF_W1T   0u          // 4096    : w1p fp16 [tap8][oc32][k32] zero-pad
#define OFF_W2T   6144u       // 16384   : w2T fp16 [tap16][oc64][c32]
#define OFF_W3T   22528u      // 18432   : w3T fp16 [tap9][oc64][c64]
#define OFF_WF    40960u      // 65536   : wfeat [2048][32]
#define OFF_PF    106496u     // 131072  : posfeat [2048][64]
#define OFF_Y0    237568u     // 8192    : y0 [64][128]
#define OFF_PP    245760u     // 262144  : pp [2048][128] head pos-term
#define OFF_H     507904u     // 1048576 : h0 [2048][512] raw K-chunk partial
#define OFF_DELTA 1556480u    // 262144  : delta [2048][128]
#define OFF_WFCT  1818624u    // 802816  : wfcT fp16 [512][3136] (k=c*49+pos)
#define OFF_C3    2621440u    // 3211264 : c3b fp16 [2048][3136]
#define OFF_H1    5832704u    // 1048576 : h1
#define OFF_H2    6881280u    // 1048576 : h2
#define OFF_H3    7929856u    // 1048576 : h3   (ws high-water 35.9 MB)

// ---------------- merged weight prep (prep + wfcT transpose) ----------------
__global__ __launch_bounds__(256) void prep_all(
    const float* __restrict__ w1, const float* __restrict__ w2,
    const float* __restrict__ w3, half_t* __restrict__ w1p,
    half_t* __restrict__ w2T, half_t* __restrict__ w3T,
    const float* __restrict__ wfc, half_t* __restrict__ wfcT) {
  __shared__ float t[32][33];
  int bx = blockIdx.x;
  if (bx < 304) {
    int g = bx * 256 + threadIdx.x;   // 77824 total
    if (g < 8192) {
      // w1p[(tap*32+oc)*32+kk], kk=kx*3+c (<24) else 0 ; w1 is [oc][c][ky*8+kx]
      int kk = g & 31, oc = (g >> 5) & 31, tap = g >> 10;
      half_t v = (half_t)0.f;
      if (kk < 24) {
        int kx = kk / 3, c = kk - 3 * kx;
        v = (half_t)(w1[oc * 192 + c * 64 + tap * 8 + kx] * (1.0f / 255.0f));
      }
      w1p[g] = v;
      return;
    }
    int g2 = g - 8192;
    if (g2 < 32768) {                          // w2T[(tap*64+oc)*32+c]
      int c = g2 & 31, oc = (g2 >> 5) & 63, tap = g2 >> 11;
      w2T[g2] = (half_t)w2[oc * 512 + c * 16 + tap];
      return;
    }
    int g3 = g2 - 32768;
    if (g3 < 36864) {                          // w3T[(tap*64+oc)*64+c]
      int c = g3 & 63, oc = (g3 >> 6) & 63, tap = g3 >> 12;
      w3T[g3] = (half_t)w3[oc * 576 + c * 9 + tap];
    }
    return;
  }
  // wfcT[n][k] = (half)wfc[k][n], k = c*49+pos : LDS-tiled transpose
  int gb = bx - 304;                           // 0..1567
  int k0 = (gb % 98) * 32, n0 = (gb / 98) * 32;
  int tx = threadIdx.x & 31, ty = threadIdx.x >> 5;  // ty 0..7
#pragma unroll
  for (int i = 0; i < 4; ++i)
    t[ty + 8 * i][tx] = wfc[(size_t)(k0 + ty + 8 * i) * 512 + n0 + tx];
  __syncthreads();
#pragma unroll
  for (int i = 0; i < 4; ++i)
    wfcT[(size_t)(n0 + ty + 8 * i) * 3136 + k0 + tx] =
        (half_t)t[tx][ty + 8 * i];
}

// ---------------- fused conv1+conv2+conv3: one block per image --------------
// LDS map (bytes): [0,10080)      conv1 staging (single buffer, 1 band fp16)
//                  [0,10368)      C2out (conv3 swizzle) -- aliases dead staging
//                  [10368,35968)  C1out (conv2 swizzle)
#define C1_BANDF 5040
#define C1_BANDV 1260
#define C1OUT_OFF 10368
#define C1A(ip, bp)                                                     \
  (C1OUT_OFF + ((ip) >> 1) * 128 +                                      \
   (((((ip) & 1) << 6) | ((bp) & 0x30)) ^ ((((ip) >> 1) & 7) << 4)) +   \
   ((bp) & 15))
#define C2A(ir, bp) \
  ((ir) * 128 + (((bp) & 0x70) ^ (((ir) & 7) << 4)) + ((bp) & 15))
__global__ __launch_bounds__(256) void conv123_mfma(
    const float* __restrict__ img, const half_t* __restrict__ w1p,
    const float* __restrict__ b1, const half_t* __restrict__ w2T,
    const float* __restrict__ b2, const half_t* __restrict__ w3T,
    const float* __restrict__ b3, half_t* __restrict__ out) {
  __shared__ __align__(16) char lds[35968];
  half_t* stag = (half_t*)lds;                 // single band buffer
  int tid = threadIdx.x;
  int li = blockIdx.x;
  int w = tid >> 6, l = tid & 63, lc = l & 15, q = l >> 4;
  const float* ib = img + (size_t)li * 21168;

  // ---- phase 1: conv1 (banded; 3-deep register prefetch, single LDS buf) ---
  half8 bfrag1[8][2];
#pragma unroll
  for (int tap = 0; tap < 8; ++tap)
#pragma unroll
    for (int t = 0; t < 2; ++t)
      bfrag1[tap][t] =
          *(const half8*)(w1p + (size_t)(tap * 32 + t * 16 + lc) * 32 + q * 8);
  float b1v[2] = {b1[lc], b1[16 + lc]};

  f32x4 fr0[5], fr1[5], fr2[5];                // 3 named prefetch sets
#define C1_LOADB(b, fr)                                               \
  {                                                                   \
    const float* src = ib + 4032 * (b);                               \
    _Pragma("unroll") for (int i = 0; i < 5; ++i) {                   \
      int g = tid + 256 * i;                                          \
      if (g < C1_BANDV) fr[i] = *(const f32x4*)(src + 4 * g);         \
    }                                                                 \
  }
#define C1_WRITEB(fr)                                                 \
  {                                                                   \
    _Pragma("unroll") for (int i = 0; i < 5; ++i) {                   \
      int g = tid + 256 * i;                                          \
      if (g < C1_BANDV) {                                             \
        half4 o;                                                      \
        _Pragma("unroll") for (int j = 0; j < 4; ++j)                 \
            o[j] = (half_t)fr[i][j];                                  \
        *(half4*)&stag[4 * g] = o;                                    \
      }                                                               \
    }                                                                 \
  }
  // compute band b (b compile-time constant in every expansion)
#define C1_COMPUTE(b)                                                 \
  for (int tile = w; tile < 5; tile += 4) {                           \
    int lp = tile * 16 + lc;                                          \
    int oyl = lp / 20, ox = lp - oyl * 20;                            \
    f32x4 acc[2];                                                     \
    acc[0] = (f32x4){0.f, 0.f, 0.f, 0.f};                             \
    acc[1] = (f32x4){0.f, 0.f, 0.f, 0.f};                             \
    _Pragma("unroll") for (int ky = 0; ky < 8; ++ky) {                \
      half8 af;                                                       \
      if (q < 3) {                                                    \
        const half_t* p = &stag[(4 * oyl + ky) * 252 + 12 * ox + q * 8]; \
        *(half4*)&af = *(const half4*)p;                              \
        *((half4*)&af + 1) = *((const half4*)(p + 4));                \
      } else {                                                        \
        _Pragma("unroll") for (int j = 0; j < 8; ++j)                 \
            af[j] = (half_t)0.f;                                      \
      }                                                               \
      acc[0] = __builtin_amdgcn_mfma_f32_16x16x32_f16(af, bfrag1[ky][0], \
                                                      acc[0], 0, 0, 0);  \
      acc[1] = __builtin_amdgcn_mfma_f32_16x16x32_f16(af, bfrag1[ky][1], \
                                                      acc[1], 0, 0, 0);  \
    }                                                                 \
    _Pragma("unroll") for (int t = 0; t < 2; ++t) {                   \
      _Pragma("unroll") for (int r = 0; r < 4; ++r) {                 \
        int ip = (b) * 80 + tile * 16 + q * 4 + r;                    \
        int ch = t * 16 + lc;                                         \
        *(half_t*)(lds + C1A(ip, 2 * ch)) =                           \
            (half_t)fmaxf(acc[t][r] + b1v[t], 0.f);                   \
      }                                                               \
    }                                                                 \
  }

  // schedule: loads 3 bands ahead; set reuse is safe because a set's
  // ds_writes were issued (regs consumed) a full band earlier.
  C1_LOADB(0, fr0); C1_LOADB(1, fr1); C1_LOADB(2, fr2);
  C1_WRITEB(fr0);
  __syncthreads();                   // band 0 visible
  C1_COMPUTE(0);
  __syncthreads();                   // band 0 reads done
  C1_LOADB(3, fr0);                  // fr0 dead since prologue write
  C1_WRITEB(fr1);
  __syncthreads();                   // band 1 visible
  C1_COMPUTE(1);
  __syncthreads();
  C1_LOADB(4, fr1);                  // fr1 dead since band-1 write
  C1_WRITEB(fr2);
  __syncthreads();                   // band 2 visible
  C1_COMPUTE(2);
  __syncthreads();
  C1_WRITEB(fr0);                    // band 3
  __syncthreads();
  C1_COMPUTE(3);
  __syncthreads();
  C1_WRITEB(fr1);                    // band 4
  __syncthreads();
  C1_COMPUTE(4);
  __syncthreads();                   // C1out complete; stag dead

  // ---- phase 2: conv2 (reads C1out; epilogue -> C2out, aliases stag) ----
  {
    half8 bfrag2[16][2];
#pragma unroll
    for (int tap = 0; tap < 16; ++tap)
#pragma unroll
      for (int j = 0; j < 2; ++j) {
        int nt = (w & 1) * 2 + j;
        bfrag2[tap][j] = *(const half8*)(
            w2T + (size_t)(tap * 64 + nt * 16 + lc) * 32 + q * 8);
      }
    float b2v[2];
#pragma unroll
    for (int j = 0; j < 2; ++j) b2v[j] = b2[(w & 1) * 32 + j * 16 + lc];

#pragma unroll
    for (int ti = 0; ti < 3; ++ti) {
      int tile = (w >> 1) + 2 * ti;               // 0..5
      int row16 = tile * 16 + lc;
      int orow = row16 < 81 ? row16 : 80;         // clamp dead rows
      int oy = orow / 9, ox = orow - oy * 9;
      f32x4 acc[2];
      acc[0] = (f32x4){0.f, 0.f, 0.f, 0.f};
      acc[1] = (f32x4){0.f, 0.f, 0.f, 0.f};
#pragma unroll
      for (int tap = 0; tap < 16; ++tap) {
        int ky = tap >> 2, kx = tap & 3;
        int ip = (2 * oy + ky) * 20 + 2 * ox + kx;
        half8 af = *(const half8*)(lds + C1A(ip, q * 16));
        acc[0] = __builtin_amdgcn_mfma_f32_16x16x32_f16(af, bfrag2[tap][0],
                                                        acc[0], 0, 0, 0);
        acc[1] = __builtin_amdgcn_mfma_f32_16x16x32_f16(af, bfrag2[tap][1],
                                                        acc[1], 0, 0, 0);
      }
#pragma unroll
      for (int j = 0; j < 2; ++j) {
#pragma unroll
        for (int r = 0; r < 4; ++r) {
          int mr = tile * 16 + q * 4 + r;
          if (mr < 81) {
            int col = (w & 1) * 32 + j * 16 + lc;
            *(half_t*)(lds + C2A(mr, 2 * col)) =
                (half_t)fmaxf(acc[j][r] + b2v[j], 0.f);
          }
        }
      }
    }
  }
  __syncthreads();   // C2out visible

  // ---- phase 3: conv3 (reads C2out; writes c3b k-order c*49+pos) ----
  {
    half8 bfrag3[9][2];
#pragma unroll
    for (int tap = 0; tap < 9; ++tap)
#pragma unroll
      for (int ch = 0; ch < 2; ++ch)
        bfrag3[tap][ch] = *(const half8*)(
            w3T + (size_t)(tap * 64 + w * 16 + lc) * 64 + ch * 32 + q * 8);
    float b3v = b3[w * 16 + lc];

    half_t* ob = out + (size_t)li * 3136;
#pragma unroll
    for (int tile = 0; tile < 4; ++tile) {
      int row16 = tile * 16 + lc;
      int orow = row16 < 49 ? row16 : 48;         // clamp dead rows
      int oy = orow / 7, ox = orow - oy * 7;
      f32x4 acc = (f32x4){0.f, 0.f, 0.f, 0.f};
#pragma unroll
      for (int tap = 0; tap < 9; ++tap) {
        int ky = tap / 3, kx = tap - ky * 3;
        int ir = (oy + ky) * 9 + ox + kx;
#pragma unroll
        for (int ch = 0; ch < 2; ++ch) {
          half8 af = *(const half8*)(lds + C2A(ir, ch * 64 + q * 16));
          acc = __builtin_amdgcn_mfma_f32_16x16x32_f16(af, bfrag3[tap][ch],
                                                       acc, 0, 0, 0);
        }
      }
#pragma unroll
      for (int r = 0; r < 4; ++r) {
        int pos2 = tile * 16 + q * 4 + r;
        if (pos2 < 49) {
          int col = w * 16 + lc;
          ob[(size_t)col * 49 + pos2] = (half_t)fmaxf(acc[r] + b3v, 0.f);
        }
      }
    }
  }
}

// ------- FC via MFMA: 128x128 tile, 4-way K-split, dbuf single barrier ------
__global__ __launch_bounds__(256) void fc_mfma(
    const half_t* __restrict__ A, const half_t* __restrict__ Bt,
    float* __restrict__ h0, float* __restrict__ h1,
    float* __restrict__ h2, float* __restrict__ h3) {
  __shared__ __align__(16) half_t As[2][128 * 40];
  __shared__ __align__(16) half_t Bs[2][128 * 40];
  int tid = threadIdx.x;
  int n0 = blockIdx.x * 128, m0 = blockIdx.y * 128;
  int kc = blockIdx.z;
  const int kofs[4] = {0, 800, 1600, 2368};
  const int kstp[4] = {25, 25, 24, 24};
  int k0 = kofs[kc], NS = kstp[kc];
  int w = tid >> 6;
  int l = tid & 63;
  int lc = l & 15, q = l >> 4;
  int srow = tid >> 2, sseg = tid & 3;

  const half_t* aP0 = A + (size_t)(m0 + srow) * 3136 + k0 + sseg * 8;
  const half_t* aP1 = A + (size_t)(m0 + srow + 64) * 3136 + k0 + sseg * 8;
  const half_t* bP0 = Bt + (size_t)(n0 + srow) * 3136 + k0 + sseg * 8;
  const half_t* bP1 = Bt + (size_t)(n0 + srow + 64) * 3136 + k0 + sseg * 8;
  uint4 aR0 = *(const uint4*)aP0, aR1 = *(const uint4*)aP1;
  uint4 bR0 = *(const uint4*)bP0, bR1 = *(const uint4*)bP1;

  f32x4 acc[2][8];
#pragma unroll
  for (int m = 0; m < 2; ++m)
#pragma unroll
    for (int t = 0; t < 8; ++t) acc[m][t] = (f32x4){0.f, 0.f, 0.f, 0.f};

  for (int s = 0; s < NS; ++s) {
    int cur = s & 1;
    *(uint4*)&As[cur][srow * 40 + sseg * 8] = aR0;
    *(uint4*)&As[cur][(srow + 64) * 40 + sseg * 8] = aR1;
    *(uint4*)&Bs[cur][srow * 40 + sseg * 8] = bR0;
    *(uint4*)&Bs[cur][(srow + 64) * 40 + sseg * 8] = bR1;
    __syncthreads();                         // the only barrier per step
    if (s + 1 < NS) {                        // prefetch overlaps MFMA below
      int o = (s + 1) * 32;
      aR0 = *(const uint4*)(aP0 + o);
      aR1 = *(const uint4*)(aP1 + o);
      bR0 = *(const uint4*)(bP0 + o);
      bR1 = *(const uint4*)(bP1 + o);
    }
    half8 af[2];
#pragma unroll
    for (int m = 0; m < 2; ++m)
      af[m] = *(const half8*)&As[cur][(w * 32 + m * 16 + lc) * 40 + q * 8];
#pragma unroll
    for (int t = 0; t < 8; ++t) {
      half8 bf = *(const half8*)&Bs[cur][(t * 16 + lc) * 40 + q * 8];
      acc[0][t] = __builtin_amdgcn_mfma_f32_16x16x32_f16(af[0], bf,
                                                         acc[0][t], 0, 0, 0);
      acc[1][t] = __builtin_amdgcn_mfma_f32_16x16x32_f16(af[1], bf,
                                                         acc[1][t], 0, 0, 0);
    }
  }
  float* H = (kc == 0) ? h0 : (kc == 1) ? h1 : (kc == 2) ? h2 : h3;
#pragma unroll
  for (int m = 0; m < 2; ++m)
#pragma unroll
    for (int t = 0; t < 8; ++t)
#pragma unroll
      for (int r = 0; r < 4; ++r) {
        int row = m0 + w * 32 + m * 16 + q * 4 + r;
        int col = n0 + t * 16 + lc;
        H[(size_t)row * 512 + col] = acc[m][t][r];
      }
}

// ---------------- mid1: wfeat(K-split) + posfeat + y0 (one launch) ----------
// grid 4608: [0,2048) wfeat one-block-per-row; [2048,2560) posfeat; rest y0.
__global__ __launch_bounds__(256) void mid1_kernel(
    const float* __restrict__ h0, const float* __restrict__ h1,
    const float* __restrict__ h2, const float* __restrict__ h3,
    const float* __restrict__ bfc, const float* __restrict__ Ww,
    const float* __restrict__ bw, float* __restrict__ wf,
    const int* __restrict__ pos, const float* __restrict__ wp1,
    const float* __restrict__ bp1, const float* __restrict__ wp2,
    const float* __restrict__ bp2, float* __restrict__ pf,
    const float* __restrict__ s0, const float* __restrict__ wpo1,
    const float* __restrict__ wv1, float* __restrict__ y0) {
  __shared__ float hsum[512];
  __shared__ float red[256];
  int bx = blockIdx.x;
  int tid = threadIdx.x;
  if (bx < 2048) {
    // ---- wfeat row bx: hsum staged once, 8-way K-split, LDS reduce ----
    int row = bx;
#pragma unroll
    for (int i = 0; i < 2; ++i) {
      int k = tid + 256 * i;
      hsum[k] = fmaxf(h0[(size_t)row * 512 + k] + h1[(size_t)row * 512 + k] +
                          h2[(size_t)row * 512 + k] +
                          h3[(size_t)row * 512 + k] + bfc[k],
                      0.f);
    }
    __syncthreads();
    int oc = tid & 31, kh = tid >> 5;            // kh 0..7
    int k0 = kh * 64;
    float acc = 0.f;
#pragma unroll 8
    for (int j = 0; j < 64; ++j)
      acc += hsum[k0 + j] * Ww[(k0 + j) * 32 + oc];
    red[tid] = acc;
    __syncthreads();
    if (kh == 0) {
      float a = bw[oc];
#pragma unroll
      for (int m = 0; m < 8; ++m) a += red[m * 32 + oc];
      wf[row * 32 + oc] = a;
    }
    return;
  }
  if (bx < 2560) {
    // ---- posfeat: one-hot MLP, one wave per row ----
    int row = ((bx - 2048) * 256 + tid) >> 6;    // 2048
    int l = tid & 63;
    int p0 = pos[row * 2], p1 = pos[row * 2 + 1];
    float t1 = fmaxf(wp1[p0 * 64 + l] + wp1[(16 + p1) * 64 + l] + bp1[l], 0.f);
    float acc = bp2[l];
#pragma unroll
    for (int k = 0; k < 64; ++k) acc += __shfl(t1, k) * wp2[k * 64 + l];
    pf[row * 64 + l] = acc;
    return;
  }
  // ---- y0 = state0 @ [wpo1|wv1] : grid (b*32+kc), thread (kh2 x n128) ----
  int g = bx - 2560;                               // 0..2047
  int b = g >> 5, kc = g & 31;                     // kc: 256-k chunk
  int n = tid & 127, kh = tid >> 7;
  const float* W = (n < 64) ? (wpo1 + n) : (wv1 + (n - 64));
  int k0 = kc * 256 + kh * 128;
  const float* s = s0 + (size_t)b * 8192 + k0;
  float acc = 0.f;
#pragma unroll 8
  for (int j = 0; j < 128; ++j) acc += s[j] * W[(size_t)(k0 + j) * 64];
  if (kh) red[n] = acc;
  __syncthreads();
  if (!kh) atomicAdd(y0 + b * 128 + n, acc + red[n]);
}

// ---------------- mid2: delta + final state + pp (head pos-term) ------------
__global__ __launch_bounds__(256) void mid2_kernel(
    const int* __restrict__ pos, const float* __restrict__ wf,
    const float* __restrict__ wpo1, const float* __restrict__ wv1,
    float* __restrict__ delta, const float* __restrict__ s0,
    const float* __restrict__ done, float* __restrict__ out_state,
    const float* __restrict__ pf, float* __restrict__ pp) {
  int bx = blockIdx.x;
  if (bx < 1024) {
    // ---- delta: 2 rows per block ----
    int row = bx * 2 + (threadIdx.x >> 7);
    int n = threadIdx.x & 127;
    const float* W = (n < 64) ? (wpo1 + n) : (wv1 + (n - 64));
    int off = pos[row * 2] * 16 + pos[row * 2 + 1];
    const float* wfr = wf + row * 32;
    float d = 0.f;
#pragma unroll
    for (int c = 0; c < 32; ++c) d += wfr[c] * W[(size_t)(c * 256 + off) * 64];
    delta[(size_t)row * 128 + n] = d;
    return;
  }
  if (bx < 1088) {
    // ---- final map state (output 2) ----
    int b = bx - 1024, tid = threadIdx.x;     // tid = spatial offset 0..255
    float s[32];
#pragma unroll
    for (int c = 0; c < 32; ++c) s[c] = s0[(size_t)b * 8192 + c * 256 + tid];
    for (int t = 0; t < TT; ++t) {
      int row = t * BB + b;
      float mask = 1.f - done[row];
      int off = pos[row * 2] * 16 + pos[row * 2 + 1];
#pragma unroll
      for (int c = 0; c < 32; ++c) s[c] *= mask;
      if (tid == off) {
#pragma unroll
        for (int c = 0; c < 32; ++c) s[c] += wf[row * 32 + c];
      }
    }
#pragma unroll
    for (int c = 0; c < 32; ++c)
      out_state[(size_t)b * 8192 + c * 256 + tid] = s[c];
    return;
  }
  // ---- pp[row][n] = sum_k pf[row][k] * Wpos[k][n] : 2 rows per block ----
  int row = (bx - 1088) * 2 + (threadIdx.x >> 7);
  int n = threadIdx.x & 127;
  const float* W = (n < 64) ? (wpo1 + n) : (wv1 + (n - 64));
  const float* pfr = pf + row * 64;
  float acc = 0.f;
#pragma unroll
  for (int k = 0; k < 64; ++k) acc += pfr[k] * W[(size_t)(8192 + k) * 64];
  pp[(size_t)row * 128 + n] = acc;
}

// ------- scan+head: y recurrence, then per-t policy/value reduce ------------
// 64 blocks x 128 thr = 2 waves. wave0 (n<64): policy; wave1: value.
__global__ __launch_bounds__(128) void scan_head_kernel(
    const float* __restrict__ y0, const float* __restrict__ done,
    const float* __restrict__ delta, const float* __restrict__ pp,
    const float* __restrict__ bpo1, const float* __restrict__ bv1,
    const float* __restrict__ wpo2, const float* __restrict__ bpo2,
    const float* __restrict__ wv2, const float* __restrict__ bv2,
    float* __restrict__ logits, float* __restrict__ vout) {
  int b = blockIdx.x;
  int n = threadIdx.x;                      // 0..127
  int l = n & 63, wv = n >> 6;
  float bias1 = wv ? bv1[l] : bpo1[l];
  float w2v[5];
  if (!wv) {
#pragma unroll
    for (int a = 0; a < 5; ++a) w2v[a] = wpo2[l * 5 + a];
  } else {
    w2v[0] = wv2[l];
  }
  float y = y0[b * 128 + n];
  for (int t = 0; t < TT; ++t) {
    int row = t * BB + b;
    y = y * (1.f - done[row]) + delta[(size_t)row * 128 + n];
    float act = fmaxf(y + pp[(size_t)row * 128 + n] + bias1, 0.f);
    if (!wv) {
#pragma unroll
      for (int a = 0; a < 5; ++a) {
        float pa = act * w2v[a];
#pragma unroll
        for (int m = 32; m >= 1; m >>= 1) pa += __shfl_xor(pa, m);
        if (l == 0) logits[row * 5 + a] = pa + bpo2[a];
      }
    } else {
      float pv = act * w2v[0];
#pragma unroll
      for (int m = 32; m >= 1; m >>= 1) pv += __shfl_xor(pv, m);
      if (l == 0) vout[row] = pv + bv2[0];
    }
  }
}

extern "C" void kernel_launch(void* const* d_in, const int* in_sizes, int n_in,
                              void* d_out, int out_size, void* d_ws, size_t ws_size,
                              hipStream_t stream) {
  const float* image = (const float*)d_in[0];
  const float* done = (const float*)d_in[1];
  const float* state0 = (const float*)d_in[2];
  const int* position = (const int*)d_in[3];
  const float* w1 = (const float*)d_in[4];
  const float* b1 = (const float*)d_in[5];
  const float* w2 = (const float*)d_in[6];
  const float* b2 = (const float*)d_in[7];
  const float* w3 = (const float*)d_in[8];
  const float* b3 = (const float*)d_in[9];
  const float* wfc = (const float*)d_in[10];
  const float* bfc = (const float*)d_in[11];
  const float* Ww = (const float*)d_in[12];
  const float* bw = (const float*)d_in[13];
  const float* wp1 = (const float*)d_in[14];
  const float* bp1 = (const float*)d_in[15];
  const float* wp2 = (const float*)d_in[16];
  const float* bp2 = (const float*)d_in[17];
  const float* wpo1 = (const float*)d_in[18];
  const float* bpo1 = (const float*)d_in[19];
  const float* wpo2 = (const float*)d_in[20];
  const float* bpo2 = (const float*)d_in[21];
  const float* wv1 = (const float*)d_in[22];
  const float* bv1 = (const float*)d_in[23];
  const float* wv2 = (const float*)d_in[24];
  const float* bv2 = (const float*)d_in[25];

  float* ws = (float*)d_ws;
  half_t* w1p = (half_t*)(ws + OFF_W1T);
  half_t* w2T = (half_t*)(ws + OFF_W2T);
  half_t* w3T = (half_t*)(ws + OFF_W3T);
  float* wf = ws + OFF_WF;
  float* pfb = ws + OFF_PF;
  float* y0 = ws + OFF_Y0;
  float* ppb = ws + OFF_PP;
  float* h0b = ws + OFF_H;
  float* h1b = ws + OFF_H1;
  float* h2b = ws + OFF_H2;
  float* h3b = ws + OFF_H3;
  float* deltab = ws + OFF_DELTA;
  half_t* wfcT = (half_t*)(ws + OFF_WFCT);
  half_t* c3b = (half_t*)(ws + OFF_C3);

  float* out = (float*)d_out;
  float* out_logits = out;            // [2048,5]
  float* out_v = out + 10240;         // [2048,1]
  float* out_state = out + 12288;     // [64,32,16,16]

  hipMemsetAsync(y0, 0, 8192 * sizeof(float), stream);
  prep_all<<<1872, 256, 0, stream>>>(w1, w2, w3, w1p, w2T, w3T, wfc, wfcT);
  conv123_mfma<<<TBR, 256, 0, stream>>>(image, w1p, b1, w2T, b2, w3T, b3, c3b);
  fc_mfma<<<dim3(4, 16, 4), 256, 0, stream>>>(c3b, wfcT, h0b, h1b, h2b, h3b);
  mid1_kernel<<<4608, 256, 0, stream>>>(h0b, h1b, h2b, h3b, bfc, Ww, bw, wf,
                                        position, wp1, bp1, wp2, bp2, pfb,
                                        state0, wpo1, wv1, y0);
  mid2_kernel<<<2112, 256, 0, stream>>>(position, wf, wpo1, wv1, deltab,
                                        state0, done, out_state, pfb, ppb);
  scan_head_kernel<<<64, 128, 0, stream>>>(y0, done, deltab, ppb, bpo1, bv1,
                                           wpo2, bpo2, wv2, bv2,
                                           out_logits, out_v);
}

// Round 16
// 436.372 us; speedup vs baseline: 1.0285x; 1.0285x over previous
//
#include <hip/hip_runtime.h>
#include <hip/hip_bf16.h>

// MapAgent: NatureCNN (3 convs + FC) -> map-write scan -> policy/value heads.
// T=32, B=64, TB=2048.
//
// R23: REVERT R22's 3-deep prefetch (regression: conv 105->118us, occupancy
// 28->20% -- longer register lifetimes cut resident waves). This restores the
// session-best R21 configuration (436.4us measured):
//  * conv123: R17 single-buf staging, 1-deep reg prefetch (105us; 6 schedule
//    mechanisms falsified on this kernel -- latency floor accepted).
//  * fc: 128x128 tiles, 4-way K-split. mid1: K-split wfeat + posfeat + y0.
//  * mid2: delta + state + pp. scan_head: fused recurrence + heads.

#define TT 32
#define BB 64
#define TBR 2048

typedef _Float16 half_t;
typedef __attribute__((ext_vector_type(4))) _Float16 half4;
typedef __attribute__((ext_vector_type(8))) _Float16 half8;
typedef __attribute__((ext_vector_type(4))) float f32x4;

// ---- workspace offsets (floats) ----
#define OFF_W1T   0u          // 4096    : w1p fp16 [tap8][oc32][k32] zero-pad
#define OFF_W2T   6144u       // 16384   : w2T fp16 [tap16][oc64][c32]
#define OFF_W3T   22528u      // 18432   : w3T fp16 [tap9][oc64][c64]
#define OFF_WF    40960u      // 65536   : wfeat [2048][32]
#define OFF_PF    106496u     // 131072  : posfeat [2048][64]
#define OFF_Y0    237568u     // 8192    : y0 [64][128]
#define OFF_PP    245760u     // 262144  : pp [2048][128] head pos-term
#define OFF_H     507904u     // 1048576 : h0 [2048][512] raw K-chunk partial
#define OFF_DELTA 1556480u    // 262144  : delta [2048][128]
#define OFF_WFCT  1818624u    // 802816  : wfcT fp16 [512][3136] (k=c*49+pos)
#define OFF_C3    2621440u    // 3211264 : c3b fp16 [2048][3136]
#define OFF_H1    5832704u    // 1048576 : h1
#define OFF_H2    6881280u    // 1048576 : h2
#define OFF_H3    7929856u    // 1048576 : h3   (ws high-water 35.9 MB)

// ---------------- merged weight prep (prep + wfcT transpose) ----------------
__global__ __launch_bounds__(256) void prep_all(
    const float* __restrict__ w1, const float* __restrict__ w2,
    const float* __restrict__ w3, half_t* __restrict__ w1p,
    half_t* __restrict__ w2T, half_t* __restrict__ w3T,
    const float* __restrict__ wfc, half_t* __restrict__ wfcT) {
  __shared__ float t[32][33];
  int bx = blockIdx.x;
  if (bx < 304) {
    int g = bx * 256 + threadIdx.x;   // 77824 total
    if (g < 8192) {
      // w1p[(tap*32+oc)*32+kk], kk=kx*3+c (<24) else 0 ; w1 is [oc][c][ky*8+kx]
      int kk = g & 31, oc = (g >> 5) & 31, tap = g >> 10;
      half_t v = (half_t)0.f;
      if (kk < 24) {
        int kx = kk / 3, c = kk - 3 * kx;
        v = (half_t)(w1[oc * 192 + c * 64 + tap * 8 + kx] * (1.0f / 255.0f));
      }
      w1p[g] = v;
      return;
    }
    int g2 = g - 8192;
    if (g2 < 32768) {                          // w2T[(tap*64+oc)*32+c]
      int c = g2 & 31, oc = (g2 >> 5) & 63, tap = g2 >> 11;
      w2T[g2] = (half_t)w2[oc * 512 + c * 16 + tap];
      return;
    }
    int g3 = g2 - 32768;
    if (g3 < 36864) {                          // w3T[(tap*64+oc)*64+c]
      int c = g3 & 63, oc = (g3 >> 6) & 63, tap = g3 >> 12;
      w3T[g3] = (half_t)w3[oc * 576 + c * 9 + tap];
    }
    return;
  }
  // wfcT[n][k] = (half)wfc[k][n], k = c*49+pos : LDS-tiled transpose
  int gb = bx - 304;                           // 0..1567
  int k0 = (gb % 98) * 32, n0 = (gb / 98) * 32;
  int tx = threadIdx.x & 31, ty = threadIdx.x >> 5;  // ty 0..7
#pragma unroll
  for (int i = 0; i < 4; ++i)
    t[ty + 8 * i][tx] = wfc[(size_t)(k0 + ty + 8 * i) * 512 + n0 + tx];
  __syncthreads();
#pragma unroll
  for (int i = 0; i < 4; ++i)
    wfcT[(size_t)(n0 + ty + 8 * i) * 3136 + k0 + tx] =
        (half_t)t[tx][ty + 8 * i];
}

// ---------------- fused conv1+conv2+conv3: one block per image (R17) --------
// LDS map (bytes): [0,10080)      conv1 staging (single buffer, 1 band fp16)
//                  [0,10368)      C2out (conv3 swizzle) -- aliases dead staging
//                  [10368,35968)  C1out (conv2 swizzle)
#define C1_BANDF 5040
#define C1_BANDV 1260
#define C1OUT_OFF 10368
#define C1A(ip, bp)                                                     \
  (C1OUT_OFF + ((ip) >> 1) * 128 +                                      \
   (((((ip) & 1) << 6) | ((bp) & 0x30)) ^ ((((ip) >> 1) & 7) << 4)) +   \
   ((bp) & 15))
#define C2A(ir, bp) \
  ((ir) * 128 + (((bp) & 0x70) ^ (((ir) & 7) << 4)) + ((bp) & 15))
__global__ __launch_bounds__(256) void conv123_mfma(
    const float* __restrict__ img, const half_t* __restrict__ w1p,
    const float* __restrict__ b1, const half_t* __restrict__ w2T,
    const float* __restrict__ b2, const half_t* __restrict__ w3T,
    const float* __restrict__ b3, half_t* __restrict__ out) {
  __shared__ __align__(16) char lds[35968];
  half_t* stag = (half_t*)lds;                 // single band buffer
  int tid = threadIdx.x;
  int li = blockIdx.x;
  int w = tid >> 6, l = tid & 63, lc = l & 15, q = l >> 4;
  const float* ib = img + (size_t)li * 21168;

  // ---- phase 1: conv1 (banded; single-buf staging, reg prefetch) ----
  half8 bfrag1[8][2];
#pragma unroll
  for (int tap = 0; tap < 8; ++tap)
#pragma unroll
    for (int t = 0; t < 2; ++t)
      bfrag1[tap][t] =
          *(const half8*)(w1p + (size_t)(tap * 32 + t * 16 + lc) * 32 + q * 8);
  float b1v[2] = {b1[lc], b1[16 + lc]};

  f32x4 fr[5];
#define C1_LOADB(b)                                                   \
  {                                                                   \
    const float* src = ib + 4032 * (b);                               \
    _Pragma("unroll") for (int i = 0; i < 5; ++i) {                   \
      int g = tid + 256 * i;                                          \
      if (g < C1_BANDV) fr[i] = *(const f32x4*)(src + 4 * g);         \
    }                                                                 \
  }
#define C1_WRITEB()                                                   \
  {                                                                   \
    _Pragma("unroll") for (int i = 0; i < 5; ++i) {                   \
      int g = tid + 256 * i;                                          \
      if (g < C1_BANDV) {                                             \
        half4 o;                                                      \
        _Pragma("unroll") for (int j = 0; j < 4; ++j)                 \
            o[j] = (half_t)fr[i][j];                                  \
        *(half4*)&stag[4 * g] = o;                                    \
      }                                                               \
    }                                                                 \
  }

  C1_LOADB(0);
  C1_WRITEB();
  __syncthreads();                             // band 0 staged & visible
  for (int b = 0; b < 5; ++b) {
    if (b < 4) C1_LOADB(b + 1);                // reg prefetch overlaps compute
    for (int tile = w; tile < 5; tile += 4) {
      int lp = tile * 16 + lc;
      int oyl = lp / 20, ox = lp - oyl * 20;
      f32x4 acc[2];
      acc[0] = (f32x4){0.f, 0.f, 0.f, 0.f};
      acc[1] = (f32x4){0.f, 0.f, 0.f, 0.f};
#pragma unroll
      for (int ky = 0; ky < 8; ++ky) {
        half8 af;
        if (q < 3) {
          const half_t* p = &stag[(4 * oyl + ky) * 252 + 12 * ox + q * 8];
          *(half4*)&af = *(const half4*)p;
          *((half4*)&af + 1) = *((const half4*)(p + 4));
        } else {
#pragma unroll
          for (int j = 0; j < 8; ++j) af[j] = (half_t)0.f;
        }
        acc[0] = __builtin_amdgcn_mfma_f32_16x16x32_f16(af, bfrag1[ky][0],
                                                        acc[0], 0, 0, 0);
        acc[1] = __builtin_amdgcn_mfma_f32_16x16x32_f16(af, bfrag1[ky][1],
                                                        acc[1], 0, 0, 0);
      }
#pragma unroll
      for (int t = 0; t < 2; ++t) {
#pragma unroll
        for (int r = 0; r < 4; ++r) {
          int ip = b * 80 + tile * 16 + q * 4 + r;
          int ch = t * 16 + lc;
          *(half_t*)(lds + C1A(ip, 2 * ch)) =
              (half_t)fmaxf(acc[t][r] + b1v[t], 0.f);
        }
      }
    }
    __syncthreads();         // stag reads of band b complete (+C1out writes)
    if (b < 4) {
      C1_WRITEB();           // overwrite single buffer with band b+1
      __syncthreads();       // band b+1 visible
    }
  }

  // ---- phase 2: conv2 (reads C1out; epilogue -> C2out, aliases stag) ----
  {
    half8 bfrag2[16][2];
#pragma unroll
    for (int tap = 0; tap < 16; ++tap)
#pragma unroll
      for (int j = 0; j < 2; ++j) {
        int nt = (w & 1) * 2 + j;
        bfrag2[tap][j] = *(const half8*)(
            w2T + (size_t)(tap * 64 + nt * 16 + lc) * 32 + q * 8);
      }
    float b2v[2];
#pragma unroll
    for (int j = 0; j < 2; ++j) b2v[j] = b2[(w & 1) * 32 + j * 16 + lc];

#pragma unroll
    for (int ti = 0; ti < 3; ++ti) {
      int tile = (w >> 1) + 2 * ti;               // 0..5
      int row16 = tile * 16 + lc;
      int orow = row16 < 81 ? row16 : 80;         // clamp dead rows
      int oy = orow / 9, ox = orow - oy * 9;
      f32x4 acc[2];
      acc[0] = (f32x4){0.f, 0.f, 0.f, 0.f};
      acc[1] = (f32x4){0.f, 0.f, 0.f, 0.f};
#pragma unroll
      for (int tap = 0; tap < 16; ++tap) {
        int ky = tap >> 2, kx = tap & 3;
        int ip = (2 * oy + ky) * 20 + 2 * ox + kx;
        half8 af = *(const half8*)(lds + C1A(ip, q * 16));
        acc[0] = __builtin_amdgcn_mfma_f32_16x16x32_f16(af, bfrag2[tap][0],
                                                        acc[0], 0, 0, 0);
        acc[1] = __builtin_amdgcn_mfma_f32_16x16x32_f16(af, bfrag2[tap][1],
                                                        acc[1], 0, 0, 0);
      }
#pragma unroll
      for (int j = 0; j < 2; ++j) {
#pragma unroll
        for (int r = 0; r < 4; ++r) {
          int mr = tile * 16 + q * 4 + r;
          if (mr < 81) {
            int col = (w & 1) * 32 + j * 16 + lc;
            *(half_t*)(lds + C2A(mr, 2 * col)) =
                (half_t)fmaxf(acc[j][r] + b2v[j], 0.f);
          }
        }
      }
    }
  }
  __syncthreads();   // C2out visible

  // ---- phase 3: conv3 (reads C2out; writes c3b k-order c*49+pos) ----
  {
    half8 bfrag3[9][2];
#pragma unroll
    for (int tap = 0; tap < 9; ++tap)
#pragma unroll
      for (int ch = 0; ch < 2; ++ch)
        bfrag3[tap][ch] = *(const half8*)(
            w3T + (size_t)(tap * 64 + w * 16 + lc) * 64 + ch * 32 + q * 8);
    float b3v = b3[w * 16 + lc];

    half_t* ob = out + (size_t)li * 3136;
#pragma unroll
    for (int tile = 0; tile < 4; ++tile) {
      int row16 = tile * 16 + lc;
      int orow = row16 < 49 ? row16 : 48;         // clamp dead rows
      int oy = orow / 7, ox = orow - oy * 7;
      f32x4 acc = (f32x4){0.f, 0.f, 0.f, 0.f};
#pragma unroll
      for (int tap = 0; tap < 9; ++tap) {
        int ky = tap / 3, kx = tap - ky * 3;
        int ir = (oy + ky) * 9 + ox + kx;
#pragma unroll
        for (int ch = 0; ch < 2; ++ch) {
          half8 af = *(const half8*)(lds + C2A(ir, ch * 64 + q * 16));
          acc = __builtin_amdgcn_mfma_f32_16x16x32_f16(af, bfrag3[tap][ch],
                                                       acc, 0, 0, 0);
        }
      }
#pragma unroll
      for (int r = 0; r < 4; ++r) {
        int pos2 = tile * 16 + q * 4 + r;
        if (pos2 < 49) {
          int col = w * 16 + lc;
          ob[(size_t)col * 49 + pos2] = (half_t)fmaxf(acc[r] + b3v, 0.f);
        }
      }
    }
  }
}

// ------- FC via MFMA: 128x128 tile, 4-way K-split, dbuf single barrier ------
__global__ __launch_bounds__(256) void fc_mfma(
    const half_t* __restrict__ A, const half_t* __restrict__ Bt,
    float* __restrict__ h0, float* __restrict__ h1,
    float* __restrict__ h2, float* __restrict__ h3) {
  __shared__ __align__(16) half_t As[2][128 * 40];
  __shared__ __align__(16) half_t Bs[2][128 * 40];
  int tid = threadIdx.x;
  int n0 = blockIdx.x * 128, m0 = blockIdx.y * 128;
  int kc = blockIdx.z;
  const int kofs[4] = {0, 800, 1600, 2368};
  const int kstp[4] = {25, 25, 24, 24};
  int k0 = kofs[kc], NS = kstp[kc];
  int w = tid >> 6;
  int l = tid & 63;
  int lc = l & 15, q = l >> 4;
  int srow = tid >> 2, sseg = tid & 3;

  const half_t* aP0 = A + (size_t)(m0 + srow) * 3136 + k0 + sseg * 8;
  const half_t* aP1 = A + (size_t)(m0 + srow + 64) * 3136 + k0 + sseg * 8;
  const half_t* bP0 = Bt + (size_t)(n0 + srow) * 3136 + k0 + sseg * 8;
  const half_t* bP1 = Bt + (size_t)(n0 + srow + 64) * 3136 + k0 + sseg * 8;
  uint4 aR0 = *(const uint4*)aP0, aR1 = *(const uint4*)aP1;
  uint4 bR0 = *(const uint4*)bP0, bR1 = *(const uint4*)bP1;

  f32x4 acc[2][8];
#pragma unroll
  for (int m = 0; m < 2; ++m)
#pragma unroll
    for (int t = 0; t < 8; ++t) acc[m][t] = (f32x4){0.f, 0.f, 0.f, 0.f};

  for (int s = 0; s < NS; ++s) {
    int cur = s & 1;
    *(uint4*)&As[cur][srow * 40 + sseg * 8] = aR0;
    *(uint4*)&As[cur][(srow + 64) * 40 + sseg * 8] = aR1;
    *(uint4*)&Bs[cur][srow * 40 + sseg * 8] = bR0;
    *(uint4*)&Bs[cur][(srow + 64) * 40 + sseg * 8] = bR1;
    __syncthreads();                         // the only barrier per step
    if (s + 1 < NS) {                        // prefetch overlaps MFMA below
      int o = (s + 1) * 32;
      aR0 = *(const uint4*)(aP0 + o);
      aR1 = *(const uint4*)(aP1 + o);
      bR0 = *(const uint4*)(bP0 + o);
      bR1 = *(const uint4*)(bP1 + o);
    }
    half8 af[2];
#pragma unroll
    for (int m = 0; m < 2; ++m)
      af[m] = *(const half8*)&As[cur][(w * 32 + m * 16 + lc) * 40 + q * 8];
#pragma unroll
    for (int t = 0; t < 8; ++t) {
      half8 bf = *(const half8*)&Bs[cur][(t * 16 + lc) * 40 + q * 8];
      acc[0][t] = __builtin_amdgcn_mfma_f32_16x16x32_f16(af[0], bf,
                                                         acc[0][t], 0, 0, 0);
      acc[1][t] = __builtin_amdgcn_mfma_f32_16x16x32_f16(af[1], bf,
                                                         acc[1][t], 0, 0, 0);
    }
  }
  float* H = (kc == 0) ? h0 : (kc == 1) ? h1 : (kc == 2) ? h2 : h3;
#pragma unroll
  for (int m = 0; m < 2; ++m)
#pragma unroll
    for (int t = 0; t < 8; ++t)
#pragma unroll
      for (int r = 0; r < 4; ++r) {
        int row = m0 + w * 32 + m * 16 + q * 4 + r;
        int col = n0 + t * 16 + lc;
        H[(size_t)row * 512 + col] = acc[m][t][r];
      }
}

// ---------------- mid1: wfeat(K-split) + posfeat + y0 (one launch) ----------
// grid 4608: [0,2048) wfeat one-block-per-row; [2048,2560) posfeat; rest y0.
__global__ __launch_bounds__(256) void mid1_kernel(
    const float* __restrict__ h0, const float* __restrict__ h1,
    const float* __restrict__ h2, const float* __restrict__ h3,
    const float* __restrict__ bfc, const float* __restrict__ Ww,
    const float* __restrict__ bw, float* __restrict__ wf,
    const int* __restrict__ pos, const float* __restrict__ wp1,
    const float* __restrict__ bp1, const float* __restrict__ wp2,
    const float* __restrict__ bp2, float* __restrict__ pf,
    const float* __restrict__ s0, const float* __restrict__ wpo1,
    const float* __restrict__ wv1, float* __restrict__ y0) {
  __shared__ float hsum[512];
  __shared__ float red[256];
  int bx = blockIdx.x;
  int tid = threadIdx.x;
  if (bx < 2048) {
    // ---- wfeat row bx: hsum staged once, 8-way K-split, LDS reduce ----
    int row = bx;
#pragma unroll
    for (int i = 0; i < 2; ++i) {
      int k = tid + 256 * i;
      hsum[k] = fmaxf(h0[(size_t)row * 512 + k] + h1[(size_t)row * 512 + k] +
                          h2[(size_t)row * 512 + k] +
                          h3[(size_t)row * 512 + k] + bfc[k],
                      0.f);
    }
    __syncthreads();
    int oc = tid & 31, kh = tid >> 5;            // kh 0..7
    int k0 = kh * 64;
    float acc = 0.f;
#pragma unroll 8
    for (int j = 0; j < 64; ++j)
      acc += hsum[k0 + j] * Ww[(k0 + j) * 32 + oc];
    red[tid] = acc;
    __syncthreads();
    if (kh == 0) {
      float a = bw[oc];
#pragma unroll
      for (int m = 0; m < 8; ++m) a += red[m * 32 + oc];
      wf[row * 32 + oc] = a;
    }
    return;
  }
  if (bx < 2560) {
    // ---- posfeat: one-hot MLP, one wave per row ----
    int row = ((bx - 2048) * 256 + tid) >> 6;    // 2048
    int l = tid & 63;
    int p0 = pos[row * 2], p1 = pos[row * 2 + 1];
    float t1 = fmaxf(wp1[p0 * 64 + l] + wp1[(16 + p1) * 64 + l] + bp1[l], 0.f);
    float acc = bp2[l];
#pragma unroll
    for (int k = 0; k < 64; ++k) acc += __shfl(t1, k) * wp2[k * 64 + l];
    pf[row * 64 + l] = acc;
    return;
  }
  // ---- y0 = state0 @ [wpo1|wv1] : grid (b*32+kc), thread (kh2 x n128) ----
  int g = bx - 2560;                               // 0..2047
  int b = g >> 5, kc = g & 31;                     // kc: 256-k chunk
  int n = tid & 127, kh = tid >> 7;
  const float* W = (n < 64) ? (wpo1 + n) : (wv1 + (n - 64));
  int k0 = kc * 256 + kh * 128;
  const float* s = s0 + (size_t)b * 8192 + k0;
  float acc = 0.f;
#pragma unroll 8
  for (int j = 0; j < 128; ++j) acc += s[j] * W[(size_t)(k0 + j) * 64];
  if (kh) red[n] = acc;
  __syncthreads();
  if (!kh) atomicAdd(y0 + b * 128 + n, acc + red[n]);
}

// ---------------- mid2: delta + final state + pp (head pos-term) ------------
__global__ __launch_bounds__(256) void mid2_kernel(
    const int* __restrict__ pos, const float* __restrict__ wf,
    const float* __restrict__ wpo1, const float* __restrict__ wv1,
    float* __restrict__ delta, const float* __restrict__ s0,
    const float* __restrict__ done, float* __restrict__ out_state,
    const float* __restrict__ pf, float* __restrict__ pp) {
  int bx = blockIdx.x;
  if (bx < 1024) {
    // ---- delta: 2 rows per block ----
    int row = bx * 2 + (threadIdx.x >> 7);
    int n = threadIdx.x & 127;
    const float* W = (n < 64) ? (wpo1 + n) : (wv1 + (n - 64));
    int off = pos[row * 2] * 16 + pos[row * 2 + 1];
    const float* wfr = wf + row * 32;
    float d = 0.f;
#pragma unroll
    for (int c = 0; c < 32; ++c) d += wfr[c] * W[(size_t)(c * 256 + off) * 64];
    delta[(size_t)row * 128 + n] = d;
    return;
  }
  if (bx < 1088) {
    // ---- final map state (output 2) ----
    int b = bx - 1024, tid = threadIdx.x;     // tid = spatial offset 0..255
    float s[32];
#pragma unroll
    for (int c = 0; c < 32; ++c) s[c] = s0[(size_t)b * 8192 + c * 256 + tid];
    for (int t = 0; t < TT; ++t) {
      int row = t * BB + b;
      float mask = 1.f - done[row];
      int off = pos[row * 2] * 16 + pos[row * 2 + 1];
#pragma unroll
      for (int c = 0; c < 32; ++c) s[c] *= mask;
      if (tid == off) {
#pragma unroll
        for (int c = 0; c < 32; ++c) s[c] += wf[row * 32 + c];
      }
    }
#pragma unroll
    for (int c = 0; c < 32; ++c)
      out_state[(size_t)b * 8192 + c * 256 + tid] = s[c];
    return;
  }
  // ---- pp[row][n] = sum_k pf[row][k] * Wpos[k][n] : 2 rows per block ----
  int row = (bx - 1088) * 2 + (threadIdx.x >> 7);
  int n = threadIdx.x & 127;
  const float* W = (n < 64) ? (wpo1 + n) : (wv1 + (n - 64));
  const float* pfr = pf + row * 64;
  float acc = 0.f;
#pragma unroll
  for (int k = 0; k < 64; ++k) acc += pfr[k] * W[(size_t)(8192 + k) * 64];
  pp[(size_t)row * 128 + n] = acc;
}

// ------- scan+head: y recurrence, then per-t policy/value reduce ------------
// 64 blocks x 128 thr = 2 waves. wave0 (n<64): policy; wave1: value.
__global__ __launch_bounds__(128) void scan_head_kernel(
    const float* __restrict__ y0, const float* __restrict__ done,
    const float* __restrict__ delta, const float* __restrict__ pp,
    const float* __restrict__ bpo1, const float* __restrict__ bv1,
    const float* __restrict__ wpo2, const float* __restrict__ bpo2,
    const float* __restrict__ wv2, const float* __restrict__ bv2,
    float* __restrict__ logits, float* __restrict__ vout) {
  int b = blockIdx.x;
  int n = threadIdx.x;                      // 0..127
  int l = n & 63, wv = n >> 6;
  float bias1 = wv ? bv1[l] : bpo1[l];
  float w2v[5];
  if (!wv) {
#pragma unroll
    for (int a = 0; a < 5; ++a) w2v[a] = wpo2[l * 5 + a];
  } else {
    w2v[0] = wv2[l];
  }
  float y = y0[b * 128 + n];
  for (int t = 0; t < TT; ++t) {
    int row = t * BB + b;
    y = y * (1.f - done[row]) + delta[(size_t)row * 128 + n];
    float act = fmaxf(y + pp[(size_t)row * 128 + n] + bias1, 0.f);
    if (!wv) {
#pragma unroll
      for (int a = 0; a < 5; ++a) {
        float pa = act * w2v[a];
#pragma unroll
        for (int m = 32; m >= 1; m >>= 1) pa += __shfl_xor(pa, m);
        if (l == 0) logits[row * 5 + a] = pa + bpo2[a];
      }
    } else {
      float pv = act * w2v[0];
#pragma unroll
      for (int m = 32; m >= 1; m >>= 1) pv += __shfl_xor(pv, m);
      if (l == 0) vout[row] = pv + bv2[0];
    }
  }
}

extern "C" void kernel_launch(void* const* d_in, const int* in_sizes, int n_in,
                              void* d_out, int out_size, void* d_ws, size_t ws_size,
                              hipStream_t stream) {
  const float* image = (const float*)d_in[0];
  const float* done = (const float*)d_in[1];
  const float* state0 = (const float*)d_in[2];
  const int* position = (const int*)d_in[3];
  const float* w1 = (const float*)d_in[4];
  const float* b1 = (const float*)d_in[5];
  const float* w2 = (const float*)d_in[6];
  const float* b2 = (const float*)d_in[7];
  const float* w3 = (const float*)d_in[8];
  const float* b3 = (const float*)d_in[9];
  const float* wfc = (const float*)d_in[10];
  const float* bfc = (const float*)d_in[11];
  const float* Ww = (const float*)d_in[12];
  const float* bw = (const float*)d_in[13];
  const float* wp1 = (const float*)d_in[14];
  const float* bp1 = (const float*)d_in[15];
  const float* wp2 = (const float*)d_in[16];
  const float* bp2 = (const float*)d_in[17];
  const float* wpo1 = (const float*)d_in[18];
  const float* bpo1 = (const float*)d_in[19];
  const float* wpo2 = (const float*)d_in[20];
  const float* bpo2 = (const float*)d_in[21];
  const float* wv1 = (const float*)d_in[22];
  const float* bv1 = (const float*)d_in[23];
  const float* wv2 = (const float*)d_in[24];
  const float* bv2 = (const float*)d_in[25];

  float* ws = (float*)d_ws;
  half_t* w1p = (half_t*)(ws + OFF_W1T);
  half_t* w2T = (half_t*)(ws + OFF_W2T);
  half_t* w3T = (half_t*)(ws + OFF_W3T);
  float* wf = ws + OFF_WF;
  float* pfb = ws + OFF_PF;
  float* y0 = ws + OFF_Y0;
  float* ppb = ws + OFF_PP;
  float* h0b = ws + OFF_H;
  float* h1b = ws + OFF_H1;
  float* h2b = ws + OFF_H2;
  float* h3b = ws + OFF_H3;
  float* deltab = ws + OFF_DELTA;
  half_t* wfcT = (half_t*)(ws + OFF_WFCT);
  half_t* c3b = (half_t*)(ws + OFF_C3);

  float* out = (float*)d_out;
  float* out_logits = out;            // [2048,5]
  float* out_v = out + 10240;         // [2048,1]
  float* out_state = out + 12288;     // [64,32,16,16]

  hipMemsetAsync(y0, 0, 8192 * sizeof(float), stream);
  prep_all<<<1872, 256, 0, stream>>>(w1, w2, w3, w1p, w2T, w3T, wfc, wfcT);
  conv123_mfma<<<TBR, 256, 0, stream>>>(image, w1p, b1, w2T, b2, w3T, b3, c3b);
  fc_mfma<<<dim3(4, 16, 4), 256, 0, stream>>>(c3b, wfcT, h0b, h1b, h2b, h3b);
  mid1_kernel<<<4608, 256, 0, stream>>>(h0b, h1b, h2b, h3b, bfc, Ww, bw, wf,
                                        position, wp1, bp1, wp2, bp2, pfb,
                                        state0, wpo1, wv1, y0);
  mid2_kernel<<<2112, 256, 0, stream>>>(position, wf, wpo1, wv1, deltab,
                                        state0, done, out_state, pfb, ppb);
  scan_head_kernel<<<64, 128, 0, stream>>>(y0, done, deltab, ppb, bpo1, bv1,
                                           wpo2, bpo2, wv2, bv2,
                                           out_logits, out_v);
}